// Round 1
// baseline (628.539 us; speedup 1.0000x reference)
//
#include <hip/hip_runtime.h>

// ---------------------------------------------------------------------------
// Complex 2-layer MAP graph convolution, pull-based CSR formulation.
//   per edge: wr = w*cos(q*(ent+cc)), wi = w*sin(...)
//   layer:  ar[n] = sum_{e: row=n} wr*xr[col] - wi*xi[col]
//           ai[n] = sum_{e: row=n} wi*xr[col] + wr*xi[col]
//           out_r = relu(ar @ W.T), out_i = relu(ai @ W.T + 2b)
//   final:  out = concat(r2,i2) @ W3.T + b3
// ---------------------------------------------------------------------------

__global__ void hist_k(const int* __restrict__ row, int* __restrict__ cnt, int E) {
  int e = blockIdx.x * blockDim.x + threadIdx.x;
  if (e < E) atomicAdd(&cnt[row[e]], 1);
}

// per-wave inclusive scan + one atomic per wave -> per-node CSR base offsets
__global__ void offs_k(const int* __restrict__ cnt, int* __restrict__ offs,
                       int* __restrict__ cursor, int* __restrict__ total, int N) {
  int n = blockIdx.x * blockDim.x + threadIdx.x;
  int lane = threadIdx.x & 63;
  int v = (n < N) ? cnt[n] : 0;
  int x = v;
#pragma unroll
  for (int d = 1; d < 64; d <<= 1) {
    int t = __shfl_up(x, d);
    if (lane >= d) x += t;
  }
  int excl = x - v;
  int wtot = __shfl(x, 63);
  int base = 0;
  if (lane == 63) base = atomicAdd(total, wtot);
  base = __shfl(base, 63);
  if (n < N) {
    offs[n] = base + excl;
    cursor[n] = base + excl;
  }
}

__global__ void scatter_k(const int* __restrict__ row, const int* __restrict__ col,
                          const float* __restrict__ wsym, const float* __restrict__ qp,
                          const float* __restrict__ ent, const float* __restrict__ cc,
                          int* __restrict__ cursor, int* __restrict__ csr_col,
                          float2* __restrict__ csr_w, int E) {
  int e = blockIdx.x * blockDim.x + threadIdx.x;
  if (e >= E) return;
  float ph = qp[0] * (ent[e] + cc[e]);
  float s, c;
  sincosf(ph, &s, &c);
  float w = wsym[e];
  int pos = atomicAdd(&cursor[row[e]], 1);
  csr_col[pos] = col[e];
  csr_w[pos] = make_float2(w * c, w * s);
}

// layer 1: complex SPMM (pull) + shared-W GEMV + bias/ReLU.
// one wave per node; lane = feature.
__global__ void __launch_bounds__(256) layer1_k(
    const float* __restrict__ xr, const float* __restrict__ xi,
    const int* __restrict__ offs, const int* __restrict__ cnt,
    const int* __restrict__ csr_col, const float2* __restrict__ csr_w,
    const float* __restrict__ W, const float* __restrict__ bias,
    float* __restrict__ out_r, float* __restrict__ out_i, int N) {
  __shared__ float sW[64 * 65];  // pad 65 -> conflict-free column reads
  for (int i = threadIdx.x; i < 64 * 64; i += 256)
    sW[(i >> 6) * 65 + (i & 63)] = W[i];
  __syncthreads();

  int n = blockIdx.x * 4 + (threadIdx.x >> 6);
  if (n >= N) return;
  n = __builtin_amdgcn_readfirstlane(n);  // wave-uniform -> scalar loads
  int lane = threadIdx.x & 63;
  int start = offs[n], num = cnt[n];

  float ar = 0.f, ai = 0.f;
  for (int t = 0; t < num; ++t) {
    int e = start + t;
    int c = csr_col[e];
    float2 w = csr_w[e];
    float vr = xr[c * 64 + lane];
    float vi = xi[c * 64 + lane];
    ar += w.x * vr - w.y * vi;
    ai += w.y * vr + w.x * vi;
  }

  float or_ = 0.f, oi_ = 0.f;
#pragma unroll
  for (int k = 0; k < 64; ++k) {
    float a = __shfl(ar, k);
    float b = __shfl(ai, k);
    float w = sW[lane * 65 + k];
    or_ = fmaf(w, a, or_);
    oi_ = fmaf(w, b, oi_);
  }
  out_r[n * 64 + lane] = fmaxf(or_, 0.f);
  out_i[n * 64 + lane] = fmaxf(oi_ + 2.f * bias[lane], 0.f);
}

// layer 2 + final projection fused: SPMM + GEMV(W2)+ReLU + [16x128] proj + b3
__global__ void __launch_bounds__(256) layer2_final_k(
    const float* __restrict__ xr, const float* __restrict__ xi,
    const int* __restrict__ offs, const int* __restrict__ cnt,
    const int* __restrict__ csr_col, const float2* __restrict__ csr_w,
    const float* __restrict__ W2, const float* __restrict__ b2,
    const float* __restrict__ W3, const float* __restrict__ b3,
    float* __restrict__ out, int N) {
  __shared__ float sW[64 * 65];
  __shared__ float sW3[16 * 132];  // pad 132
  for (int i = threadIdx.x; i < 64 * 64; i += 256)
    sW[(i >> 6) * 65 + (i & 63)] = W2[i];
  for (int i = threadIdx.x; i < 16 * 128; i += 256)
    sW3[(i >> 7) * 132 + (i & 127)] = W3[i];
  __syncthreads();

  int n = blockIdx.x * 4 + (threadIdx.x >> 6);
  if (n >= N) return;
  n = __builtin_amdgcn_readfirstlane(n);
  int lane = threadIdx.x & 63;
  int start = offs[n], num = cnt[n];

  float ar = 0.f, ai = 0.f;
  for (int t = 0; t < num; ++t) {
    int e = start + t;
    int c = csr_col[e];
    float2 w = csr_w[e];
    float vr = xr[c * 64 + lane];
    float vi = xi[c * 64 + lane];
    ar += w.x * vr - w.y * vi;
    ai += w.y * vr + w.x * vi;
  }

  float or_ = 0.f, oi_ = 0.f;
#pragma unroll
  for (int k = 0; k < 64; ++k) {
    float a = __shfl(ar, k);
    float b = __shfl(ai, k);
    float w = sW[lane * 65 + k];
    or_ = fmaf(w, a, or_);
    oi_ = fmaf(w, b, oi_);
  }
  float hr = fmaxf(or_, 0.f);
  float hi = fmaxf(oi_ + 2.f * b2[lane], 0.f);

  // final projection: out[n][o] = sum_{k<128} h[k]*W3[o][k] + b3[o]
  // lane = (q<<4) | o ; lane handles k in [q*32, q*32+32)
  int o = lane & 15, q = lane >> 4;
  float acc = 0.f;
#pragma unroll
  for (int j = 0; j < 32; ++j) {
    int src = ((q & 1) << 5) + j;      // source lane for h_r / h_i
    float va = __shfl(hr, src);
    float vb = __shfl(hi, src);
    float a = (q < 2) ? va : vb;
    acc = fmaf(sW3[o * 132 + (q << 5) + j], a, acc);
  }
  acc += __shfl_xor(acc, 16);
  acc += __shfl_xor(acc, 32);
  if (lane < 16) out[n * 16 + o] = acc + b3[o];
}

extern "C" void kernel_launch(void* const* d_in, const int* in_sizes, int n_in,
                              void* d_out, int out_size, void* d_ws, size_t ws_size,
                              hipStream_t stream) {
  const float* xr   = (const float*)d_in[0];
  const float* xi   = (const float*)d_in[1];
  const float* wsym = (const float*)d_in[2];
  const float* qp   = (const float*)d_in[3];
  const float* ent  = (const float*)d_in[4];
  const float* cc   = (const float*)d_in[5];
  const float* W1   = (const float*)d_in[6];
  const float* b1   = (const float*)d_in[7];
  const float* W2   = (const float*)d_in[8];
  const float* b2   = (const float*)d_in[9];
  const float* W3   = (const float*)d_in[10];
  const float* b3   = (const float*)d_in[11];
  const int*   row  = (const int*)d_in[12];
  const int*   col  = (const int*)d_in[13];
  const int N = in_sizes[0] / 64;
  const int E = in_sizes[2];
  float* out = (float*)d_out;

  char* ws = (char*)d_ws;
  size_t off = 0;
  auto alloc = [&](size_t bytes) -> void* {
    void* p = ws + off;
    off += (bytes + 255) & ~(size_t)255;
    return p;
  };
  int*    cnt     = (int*)alloc((size_t)N * 4);
  int*    offs    = (int*)alloc((size_t)N * 4);
  int*    cursor  = (int*)alloc((size_t)N * 4);
  int*    total   = (int*)alloc(256);
  int*    csr_col = (int*)alloc((size_t)E * 4);
  float2* csr_w   = (float2*)alloc((size_t)E * 8);
  float*  b_r     = (float*)alloc((size_t)N * 64 * 4);
  float*  b_i     = (float*)alloc((size_t)N * 64 * 4);

  hipMemsetAsync(cnt, 0, (size_t)N * 4, stream);
  hipMemsetAsync(total, 0, 4, stream);
  hist_k<<<(E + 255) / 256, 256, 0, stream>>>(row, cnt, E);
  offs_k<<<(N + 255) / 256, 256, 0, stream>>>(cnt, offs, cursor, total, N);
  scatter_k<<<(E + 255) / 256, 256, 0, stream>>>(row, col, wsym, qp, ent, cc,
                                                 cursor, csr_col, csr_w, E);
  int nb = (N + 3) / 4;
  layer1_k<<<nb, 256, 0, stream>>>(xr, xi, offs, cnt, csr_col, csr_w,
                                   W1, b1, b_r, b_i, N);
  layer2_final_k<<<nb, 256, 0, stream>>>(b_r, b_i, offs, cnt, csr_col, csr_w,
                                         W2, b2, W3, b3, out, N);
}

// Round 2
// 321.423 us; speedup vs baseline: 1.9555x; 1.9555x over previous
//
#include <hip/hip_runtime.h>

// ---------------------------------------------------------------------------
// Complex 2-layer MAP graph convolution, pull-based CSR.
// Round 1: ILP-batched gather (4 edges in flight, scalar col/weight loads),
// LDS-broadcast GEMV (8 nodes/wave amortize W), interleaved hidden activations.
// ---------------------------------------------------------------------------

#define NPW 8  // nodes per wave

__global__ void hist_k(const int* __restrict__ row, int* __restrict__ cnt, int E) {
  int e = blockIdx.x * blockDim.x + threadIdx.x;
  if (e < E) atomicAdd(&cnt[row[e]], 1);
}

// per-wave inclusive scan + one atomic per wave -> per-node CSR base offsets
__global__ void offs_k(const int* __restrict__ cnt, int* __restrict__ offs,
                       int* __restrict__ cursor, int* __restrict__ total, int N) {
  int n = blockIdx.x * blockDim.x + threadIdx.x;
  int lane = threadIdx.x & 63;
  int v = (n < N) ? cnt[n] : 0;
  int x = v;
#pragma unroll
  for (int d = 1; d < 64; d <<= 1) {
    int t = __shfl_up(x, d);
    if (lane >= d) x += t;
  }
  int excl = x - v;
  int wtot = __shfl(x, 63);
  int base = 0;
  if (lane == 63) base = atomicAdd(total, wtot);
  base = __shfl(base, 63);
  if (n < N) {
    offs[n] = base + excl;
    cursor[n] = base + excl;
  }
}

__global__ void scatter_k(const int* __restrict__ row, const int* __restrict__ col,
                          const float* __restrict__ wsym, const float* __restrict__ qp,
                          const float* __restrict__ ent, const float* __restrict__ cc,
                          int* __restrict__ cursor, int* __restrict__ csr_col,
                          float2* __restrict__ csr_w, int E) {
  int e = blockIdx.x * blockDim.x + threadIdx.x;
  if (e >= E) return;
  float ph = qp[0] * (ent[e] + cc[e]);
  float s, c;
  sincosf(ph, &s, &c);
  float w = wsym[e];
  int pos = atomicAdd(&cursor[row[e]], 1);
  csr_col[pos] = col[e];
  csr_w[pos] = make_float2(w * c, w * s);
}

// ---- layer 1: SPMM(xr,xi separate) + GEMV(W1) + bias/ReLU -> interleaved Hc
__global__ void __launch_bounds__(256) layer1_k(
    const float* __restrict__ xr, const float* __restrict__ xi,
    const int* __restrict__ offs, const int* __restrict__ cnt,
    const int* __restrict__ csr_col, const float2* __restrict__ csr_w,
    const float* __restrict__ W, const float* __restrict__ bias,
    float2* __restrict__ Hc, int N) {
  __shared__ float sW[64 * 68];  // stride 68 -> 16B-aligned rows
  __shared__ float s_a[4][64];
  __shared__ float s_b[4][64];
  for (int i = threadIdx.x; i < 64 * 64; i += 256)
    sW[(i >> 6) * 68 + (i & 63)] = W[i];
  __syncthreads();
  const int w = threadIdx.x >> 6, lane = threadIdx.x & 63;
  const float bl = 2.f * bias[lane];
  int n0 = (blockIdx.x * 4 + w) * NPW;
#pragma nounroll
  for (int ni = 0; ni < NPW; ++ni) {
    int n = n0 + ni;
    if (n >= N) break;
    int start = __builtin_amdgcn_readfirstlane(offs[n]);
    int num = __builtin_amdgcn_readfirstlane(cnt[n]);
    float ar = 0.f, ai = 0.f;
    int t = 0;
    for (; t + 4 <= num; t += 4) {  // 4 edges in flight
      int e = start + t;
      int c0 = csr_col[e + 0], c1 = csr_col[e + 1];
      int c2 = csr_col[e + 2], c3 = csr_col[e + 3];
      float2 w0 = csr_w[e + 0], w1 = csr_w[e + 1];
      float2 w2 = csr_w[e + 2], w3 = csr_w[e + 3];
      float r0 = xr[c0 * 64 + lane], i0 = xi[c0 * 64 + lane];
      float r1 = xr[c1 * 64 + lane], i1 = xi[c1 * 64 + lane];
      float r2 = xr[c2 * 64 + lane], i2 = xi[c2 * 64 + lane];
      float r3 = xr[c3 * 64 + lane], i3 = xi[c3 * 64 + lane];
      ar += w0.x * r0 - w0.y * i0; ai += w0.y * r0 + w0.x * i0;
      ar += w1.x * r1 - w1.y * i1; ai += w1.y * r1 + w1.x * i1;
      ar += w2.x * r2 - w2.y * i2; ai += w2.y * r2 + w2.x * i2;
      ar += w3.x * r3 - w3.y * i3; ai += w3.y * r3 + w3.x * i3;
    }
    for (; t < num; ++t) {
      int e = start + t;
      int c = csr_col[e];
      float2 wv = csr_w[e];
      float r = xr[c * 64 + lane], im = xi[c * 64 + lane];
      ar += wv.x * r - wv.y * im;
      ai += wv.y * r + wv.x * im;
    }
    // wave-local staging (no barrier: DS ops are in-order within a wave)
    s_a[w][lane] = ar;
    s_b[w][lane] = ai;
    float outr = 0.f, outi = 0.f;
#pragma unroll
    for (int k0 = 0; k0 < 64; k0 += 4) {
      float4 a4 = *(const float4*)&s_a[w][k0];     // broadcast
      float4 b4 = *(const float4*)&s_b[w][k0];     // broadcast
      float4 w4 = *(const float4*)&sW[lane * 68 + k0];
      outr = fmaf(w4.w, a4.w, fmaf(w4.z, a4.z, fmaf(w4.y, a4.y, fmaf(w4.x, a4.x, outr))));
      outi = fmaf(w4.w, b4.w, fmaf(w4.z, b4.z, fmaf(w4.y, b4.y, fmaf(w4.x, b4.x, outi))));
    }
    Hc[n * 64 + lane] = make_float2(fmaxf(outr, 0.f), fmaxf(outi + bl, 0.f));
  }
}

// ---- layer 2 + final [16x128] projection fused
__global__ void __launch_bounds__(256) layer2_k(
    const float2* __restrict__ Hc,
    const int* __restrict__ offs, const int* __restrict__ cnt,
    const int* __restrict__ csr_col, const float2* __restrict__ csr_w,
    const float* __restrict__ W2, const float* __restrict__ b2,
    const float* __restrict__ W3, const float* __restrict__ b3,
    float* __restrict__ out, int N) {
  __shared__ float sW[64 * 68];
  __shared__ float s_a[4][64];
  __shared__ float s_b[4][64];
  for (int i = threadIdx.x; i < 64 * 64; i += 256)
    sW[(i >> 6) * 68 + (i & 63)] = W2[i];
  __syncthreads();
  const int w = threadIdx.x >> 6, lane = threadIdx.x & 63;
  const int o = lane & 15, q = lane >> 4;
  const float bl = 2.f * b2[lane];
  float w3r[32];  // this lane's W3[o][q*32 .. q*32+31] slice
#pragma unroll
  for (int j = 0; j < 32; j += 4)
    *(float4*)&w3r[j] = *(const float4*)&W3[o * 128 + q * 32 + j];
  const float b3v = b3[o];
  int n0 = (blockIdx.x * 4 + w) * NPW;
#pragma nounroll
  for (int ni = 0; ni < NPW; ++ni) {
    int n = n0 + ni;
    if (n >= N) break;
    int start = __builtin_amdgcn_readfirstlane(offs[n]);
    int num = __builtin_amdgcn_readfirstlane(cnt[n]);
    float ar = 0.f, ai = 0.f;
    int t = 0;
    for (; t + 4 <= num; t += 4) {
      int e = start + t;
      int c0 = csr_col[e + 0], c1 = csr_col[e + 1];
      int c2 = csr_col[e + 2], c3 = csr_col[e + 3];
      float2 w0 = csr_w[e + 0], w1 = csr_w[e + 1];
      float2 w2 = csr_w[e + 2], w3 = csr_w[e + 3];
      float2 v0 = Hc[c0 * 64 + lane];
      float2 v1 = Hc[c1 * 64 + lane];
      float2 v2 = Hc[c2 * 64 + lane];
      float2 v3 = Hc[c3 * 64 + lane];
      ar += w0.x * v0.x - w0.y * v0.y; ai += w0.y * v0.x + w0.x * v0.y;
      ar += w1.x * v1.x - w1.y * v1.y; ai += w1.y * v1.x + w1.x * v1.y;
      ar += w2.x * v2.x - w2.y * v2.y; ai += w2.y * v2.x + w2.x * v2.y;
      ar += w3.x * v3.x - w3.y * v3.y; ai += w3.y * v3.x + w3.x * v3.y;
    }
    for (; t < num; ++t) {
      int e = start + t;
      int c = csr_col[e];
      float2 wv = csr_w[e];
      float2 v = Hc[c * 64 + lane];
      ar += wv.x * v.x - wv.y * v.y;
      ai += wv.y * v.x + wv.x * v.y;
    }
    s_a[w][lane] = ar;
    s_b[w][lane] = ai;
    float outr = 0.f, outi = 0.f;
#pragma unroll
    for (int k0 = 0; k0 < 64; k0 += 4) {
      float4 a4 = *(const float4*)&s_a[w][k0];
      float4 b4 = *(const float4*)&s_b[w][k0];
      float4 w4 = *(const float4*)&sW[lane * 68 + k0];
      outr = fmaf(w4.w, a4.w, fmaf(w4.z, a4.z, fmaf(w4.y, a4.y, fmaf(w4.x, a4.x, outr))));
      outi = fmaf(w4.w, b4.w, fmaf(w4.z, b4.z, fmaf(w4.y, b4.y, fmaf(w4.x, b4.x, outi))));
    }
    float hr = fmaxf(outr, 0.f);
    float hi = fmaxf(outi + bl, 0.f);
    // final projection: lane (q,o) accumulates k in [q*32, q*32+32)
    s_a[w][lane] = hr;   // in-order DS: overwrites only after GEMV reads issued
    s_b[w][lane] = hi;
    const float* hp = (q < 2) ? &s_a[w][(q & 1) * 32] : &s_b[w][(q & 1) * 32];
    float acc = 0.f;
#pragma unroll
    for (int j = 0; j < 32; j += 4) {
      float4 h4 = *(const float4*)&hp[j];
      acc = fmaf(w3r[j + 3], h4.w, fmaf(w3r[j + 2], h4.z,
            fmaf(w3r[j + 1], h4.y, fmaf(w3r[j + 0], h4.x, acc))));
    }
    acc += __shfl_xor(acc, 16);
    acc += __shfl_xor(acc, 32);
    if (lane < 16) out[n * 16 + o] = acc + b3v;
  }
}

extern "C" void kernel_launch(void* const* d_in, const int* in_sizes, int n_in,
                              void* d_out, int out_size, void* d_ws, size_t ws_size,
                              hipStream_t stream) {
  const float* xr   = (const float*)d_in[0];
  const float* xi   = (const float*)d_in[1];
  const float* wsym = (const float*)d_in[2];
  const float* qp   = (const float*)d_in[3];
  const float* ent  = (const float*)d_in[4];
  const float* cc   = (const float*)d_in[5];
  const float* W1   = (const float*)d_in[6];
  const float* b1   = (const float*)d_in[7];
  const float* W2   = (const float*)d_in[8];
  const float* b2   = (const float*)d_in[9];
  const float* W3   = (const float*)d_in[10];
  const float* b3   = (const float*)d_in[11];
  const int*   row  = (const int*)d_in[12];
  const int*   col  = (const int*)d_in[13];
  const int N = in_sizes[0] / 64;
  const int E = in_sizes[2];
  float* out = (float*)d_out;

  char* ws = (char*)d_ws;
  size_t off = 0;
  auto alloc = [&](size_t bytes) -> void* {
    void* p = ws + off;
    off += (bytes + 255) & ~(size_t)255;
    return p;
  };
  int*    cnt     = (int*)alloc((size_t)N * 4);
  int*    offs    = (int*)alloc((size_t)N * 4);
  int*    cursor  = (int*)alloc((size_t)N * 4);
  int*    total   = (int*)alloc(256);
  int*    csr_col = (int*)alloc((size_t)E * 4);
  float2* csr_w   = (float2*)alloc((size_t)E * 8);
  float2* Hc      = (float2*)alloc((size_t)N * 64 * 8);

  hipMemsetAsync(cnt, 0, (size_t)N * 4, stream);
  hipMemsetAsync(total, 0, 4, stream);
  hist_k<<<(E + 255) / 256, 256, 0, stream>>>(row, cnt, E);
  offs_k<<<(N + 255) / 256, 256, 0, stream>>>(cnt, offs, cursor, total, N);
  scatter_k<<<(E + 255) / 256, 256, 0, stream>>>(row, col, wsym, qp, ent, cc,
                                                 cursor, csr_col, csr_w, E);
  int nb = (N + 4 * NPW - 1) / (4 * NPW);
  layer1_k<<<nb, 256, 0, stream>>>(xr, xi, offs, cnt, csr_col, csr_w,
                                   W1, b1, Hc, N);
  layer2_k<<<nb, 256, 0, stream>>>(Hc, offs, cnt, csr_col, csr_w,
                                   W2, b2, W3, b3, out, N);
}

// Round 3
// 307.731 us; speedup vs baseline: 2.0425x; 1.0445x over previous
//
#include <hip/hip_runtime.h>
#include <hip/hip_bf16.h>

// ---------------------------------------------------------------------------
// Complex 2-layer MAP graph conv. Round 2:
//  - activations packed bf16x2-in-u32 (halves gather bytes; L3-resident table)
//  - GEMV + final projection on MFMA (16x16x32 bf16), wave-local LDS staging,
//    zero barriers in the hot loop
//  - 8-deep edge ILP with scalar (SGPR) col/weight loads
// ---------------------------------------------------------------------------

typedef __attribute__((ext_vector_type(8))) short short8;
typedef __attribute__((ext_vector_type(4))) float f32x4;

#define LW 72    // LDS row stride (bf16) for 64-wide rows: 2-way-bank-safe, 16B-aligned
#define LW3 136  // LDS row stride (bf16) for 128-wide proj rows

__device__ __forceinline__ unsigned short bfbits(float f) {
  __hip_bfloat16 h = __float2bfloat16(f);
  return __bfloat16_as_ushort(h);
}
__device__ __forceinline__ unsigned pack2(float re, float im) {
  return ((unsigned)bfbits(im) << 16) | (unsigned)bfbits(re);
}

// ---- CSR build ------------------------------------------------------------
__global__ void hist_k(const int* __restrict__ row, int* __restrict__ cnt, int E) {
  int e = blockIdx.x * blockDim.x + threadIdx.x;
  if (e < E) atomicAdd(&cnt[row[e]], 1);
}

__global__ void offs_k(const int* __restrict__ cnt, int* __restrict__ offs,
                       int* __restrict__ cursor, int* __restrict__ total, int N) {
  int n = blockIdx.x * blockDim.x + threadIdx.x;
  int lane = threadIdx.x & 63;
  int v = (n < N) ? cnt[n] : 0;
  int x = v;
#pragma unroll
  for (int d = 1; d < 64; d <<= 1) {
    int t = __shfl_up(x, d);
    if (lane >= d) x += t;
  }
  int excl = x - v;
  int wtot = __shfl(x, 63);
  int base = 0;
  if (lane == 63) base = atomicAdd(total, wtot);
  base = __shfl(base, 63);
  if (n < N) {
    offs[n] = base + excl;
    cursor[n] = base + excl;
  }
}

__global__ void scatter_k(const int* __restrict__ row, const int* __restrict__ col,
                          const float* __restrict__ wsym, const float* __restrict__ qp,
                          const float* __restrict__ ent, const float* __restrict__ cc,
                          int* __restrict__ cursor, int* __restrict__ csr_col,
                          float2* __restrict__ csr_w, int E) {
  int e = blockIdx.x * blockDim.x + threadIdx.x;
  if (e >= E) return;
  float ph = qp[0] * (ent[e] + cc[e]);
  float s, c;
  sincosf(ph, &s, &c);
  float w = wsym[e];
  int pos = atomicAdd(&cursor[row[e]], 1);
  csr_col[pos] = col[e];
  csr_w[pos] = make_float2(w * c, w * s);
}

// ---- pack input features to bf16x2 u32 ------------------------------------
__global__ void conv_k(const float4* __restrict__ xr, const float4* __restrict__ xi,
                       uint4* __restrict__ xc, int n4) {
  int i = blockIdx.x * 256 + threadIdx.x;
  if (i >= n4) return;
  float4 r = xr[i], m = xi[i];
  xc[i] = make_uint4(pack2(r.x, m.x), pack2(r.y, m.y), pack2(r.z, m.z), pack2(r.w, m.w));
}

// ---- complex SPMM gather for one node (lane = feature) ---------------------
__device__ __forceinline__ void gather_node(
    const unsigned* __restrict__ tbl, const int* __restrict__ ccol,
    const float2* __restrict__ cw, int start, int num, int lane,
    float& ar_out, float& ai_out) {
  float ar = 0.f, ai = 0.f;
  int t = 0;
  for (; t + 8 <= num; t += 8) {  // 8 edges in flight
    unsigned v[8];
    float2 w[8];
#pragma unroll
    for (int j = 0; j < 8; ++j) {
      int c = ccol[start + t + j];          // uniform -> s_load
      v[j] = tbl[(size_t)c * 64 + lane];
      w[j] = cw[start + t + j];             // uniform -> s_load
    }
#pragma unroll
    for (int j = 0; j < 8; ++j) {
      float vr = __uint_as_float(v[j] << 16);
      float vi = __uint_as_float(v[j] & 0xffff0000u);
      ar += w[j].x * vr - w[j].y * vi;
      ai += w[j].y * vr + w[j].x * vi;
    }
  }
  for (; t < num; ++t) {
    int c = ccol[start + t];
    unsigned u = tbl[(size_t)c * 64 + lane];
    float2 w = cw[start + t];
    float vr = __uint_as_float(u << 16);
    float vi = __uint_as_float(u & 0xffff0000u);
    ar += w.x * vr - w.y * vi;
    ai += w.y * vr + w.x * vi;
  }
  ar_out = ar;
  ai_out = ai;
}

// ---- SPMM(16 nodes) + MFMA GEMV; returns C-frags ---------------------------
// A-frag (16x16x32 bf16): lane holds A[lane&15][(lane>>4)*8 + j]
// B-frag:                 lane holds B[(lane>>4)*8 + j][lane&15] = W[lane&15][k]
// C/D: col=lane&15, row=(lane>>4)*4+reg   [verified layout]
struct Acc {
  f32x4 r[4], i[4];
};

__device__ __forceinline__ Acc spmm_gemv(
    const unsigned* __restrict__ tbl, const int* __restrict__ offs,
    const int* __restrict__ cnt, const int* __restrict__ ccol,
    const float2* __restrict__ cw, const short* __restrict__ sW,
    short* ar_lds, short* ai_lds, int n0, int N, int lane) {
  const int c16 = lane & 15, q16 = lane >> 4;
  for (int ni = 0; ni < 16; ++ni) {
    int n = n0 + ni;
    float ar = 0.f, ai = 0.f;
    if (n < N) {
      int start = __builtin_amdgcn_readfirstlane(offs[n]);
      int num = __builtin_amdgcn_readfirstlane(cnt[n]);
      gather_node(tbl, ccol, cw, start, num, lane, ar, ai);
    }
    ar_lds[ni * LW + lane] = (short)bfbits(ar);
    ai_lds[ni * LW + lane] = (short)bfbits(ai);
  }
  short8 a_r[2], a_i[2];
#pragma unroll
  for (int ks = 0; ks < 2; ++ks) {
    int off = c16 * LW + ks * 32 + q16 * 8;
    a_r[ks] = *(const short8*)&ar_lds[off];
    a_i[ks] = *(const short8*)&ai_lds[off];
  }
  Acc acc;
#pragma unroll
  for (int nt = 0; nt < 4; ++nt) {
    acc.r[nt] = (f32x4){0.f, 0.f, 0.f, 0.f};
    acc.i[nt] = (f32x4){0.f, 0.f, 0.f, 0.f};
  }
#pragma unroll
  for (int nt = 0; nt < 4; ++nt)
#pragma unroll
    for (int ks = 0; ks < 2; ++ks) {
      short8 b = *(const short8*)&sW[(nt * 16 + c16) * LW + ks * 32 + q16 * 8];
      acc.r[nt] = __builtin_amdgcn_mfma_f32_16x16x32_bf16(a_r[ks], b, acc.r[nt], 0, 0, 0);
      acc.i[nt] = __builtin_amdgcn_mfma_f32_16x16x32_bf16(a_i[ks], b, acc.i[nt], 0, 0, 0);
    }
  return acc;
}

// ---- layer 1: produces packed Hc ------------------------------------------
__global__ void __launch_bounds__(256) layer1_k(
    const unsigned* __restrict__ xc,
    const int* __restrict__ offs, const int* __restrict__ cnt,
    const int* __restrict__ ccol, const float2* __restrict__ cw,
    const float* __restrict__ W, const float* __restrict__ bias,
    unsigned* __restrict__ Hc, int N) {
  __shared__ __align__(16) short sW[64 * LW];
  __shared__ __align__(16) short s_act[4][2][16 * LW];
  for (int i = threadIdx.x; i < 64 * 64; i += 256)
    sW[(i >> 6) * LW + (i & 63)] = (short)bfbits(W[i]);
  __syncthreads();
  const int w = threadIdx.x >> 6, lane = threadIdx.x & 63;
  const int c16 = lane & 15, q16 = lane >> 4;
  int n0 = (blockIdx.x * 4 + w) * 16;
  if (n0 >= N) return;
  float bl[4];
#pragma unroll
  for (int nt = 0; nt < 4; ++nt) bl[nt] = 2.f * bias[nt * 16 + c16];

  Acc acc = spmm_gemv(xc, offs, cnt, ccol, cw, sW,
                      &s_act[w][0][0], &s_act[w][1][0], n0, N, lane);
#pragma unroll
  for (int nt = 0; nt < 4; ++nt)
#pragma unroll
    for (int r = 0; r < 4; ++r) {
      int node = n0 + q16 * 4 + r;
      if (node < N) {
        float hr = fmaxf(acc.r[nt][r], 0.f);
        float hi = fmaxf(acc.i[nt][r] + bl[nt], 0.f);
        Hc[(size_t)node * 64 + nt * 16 + c16] = pack2(hr, hi);
      }
    }
}

// ---- layer 2 + final [16x128] projection (MFMA, interleaved k) ------------
__global__ void __launch_bounds__(256) layer2_k(
    const unsigned* __restrict__ Hc,
    const int* __restrict__ offs, const int* __restrict__ cnt,
    const int* __restrict__ ccol, const float2* __restrict__ cw,
    const float* __restrict__ W2, const float* __restrict__ b2,
    const float* __restrict__ W3, const float* __restrict__ b3,
    float* __restrict__ out, int N) {
  __shared__ __align__(16) short sW[64 * LW];
  __shared__ __align__(16) short sW3p[16 * LW3];
  __shared__ __align__(16) short s_act[4][2][16 * LW];
  for (int i = threadIdx.x; i < 64 * 64; i += 256)
    sW[(i >> 6) * LW + (i & 63)] = (short)bfbits(W2[i]);
  // interleaved k' = 2f + (0:real,1:imag)  ->  source W3[o][f + 64*ri]
  for (int i = threadIdx.x; i < 16 * 128; i += 256) {
    int o = i >> 7, kp = i & 127;
    sW3p[o * LW3 + kp] = (short)bfbits(W3[o * 128 + (kp >> 1) + 64 * (kp & 1)]);
  }
  __syncthreads();
  const int w = threadIdx.x >> 6, lane = threadIdx.x & 63;
  const int c16 = lane & 15, q16 = lane >> 4;
  int n0 = (blockIdx.x * 4 + w) * 16;
  if (n0 >= N) return;
  float bl[4];
#pragma unroll
  for (int nt = 0; nt < 4; ++nt) bl[nt] = 2.f * b2[nt * 16 + c16];

  Acc acc = spmm_gemv(Hc, offs, cnt, ccol, cw, sW,
                      &s_act[w][0][0], &s_act[w][1][0], n0, N, lane);

  // stage h (packed r,i per feature) into proj buffer reusing act LDS
  unsigned* pb = (unsigned*)&s_act[w][0][0];  // [16][68] u32 rows (=136 bf16)
#pragma unroll
  for (int nt = 0; nt < 4; ++nt)
#pragma unroll
    for (int r = 0; r < 4; ++r) {
      float hr = fmaxf(acc.r[nt][r], 0.f);
      float hi = fmaxf(acc.i[nt][r] + bl[nt], 0.f);
      pb[(q16 * 4 + r) * 68 + nt * 16 + c16] = pack2(hr, hi);
    }
  f32x4 po = {0.f, 0.f, 0.f, 0.f};
#pragma unroll
  for (int ks = 0; ks < 4; ++ks) {
    short8 a = *(const short8*)((const short*)pb + c16 * LW3 + ks * 32 + q16 * 8);
    short8 b = *(const short8*)&sW3p[c16 * LW3 + ks * 32 + q16 * 8];
    po = __builtin_amdgcn_mfma_f32_16x16x32_bf16(a, b, po, 0, 0, 0);
  }
  float b3v = b3[c16];
#pragma unroll
  for (int r = 0; r < 4; ++r) {
    int node = n0 + q16 * 4 + r;
    if (node < N) out[(size_t)node * 16 + c16] = po[r] + b3v;
  }
}

extern "C" void kernel_launch(void* const* d_in, const int* in_sizes, int n_in,
                              void* d_out, int out_size, void* d_ws, size_t ws_size,
                              hipStream_t stream) {
  const float* xr   = (const float*)d_in[0];
  const float* xi   = (const float*)d_in[1];
  const float* wsym = (const float*)d_in[2];
  const float* qp   = (const float*)d_in[3];
  const float* ent  = (const float*)d_in[4];
  const float* cc   = (const float*)d_in[5];
  const float* W1   = (const float*)d_in[6];
  const float* b1   = (const float*)d_in[7];
  const float* W2   = (const float*)d_in[8];
  const float* b2   = (const float*)d_in[9];
  const float* W3   = (const float*)d_in[10];
  const float* b3   = (const float*)d_in[11];
  const int*   row  = (const int*)d_in[12];
  const int*   col  = (const int*)d_in[13];
  const int N = in_sizes[0] / 64;
  const int E = in_sizes[2];
  float* out = (float*)d_out;

  char* ws = (char*)d_ws;
  size_t off = 0;
  auto alloc = [&](size_t bytes) -> void* {
    void* p = ws + off;
    off += (bytes + 255) & ~(size_t)255;
    return p;
  };
  int*      cnt     = (int*)alloc((size_t)N * 4);
  int*      offs    = (int*)alloc((size_t)N * 4);
  int*      cursor  = (int*)alloc((size_t)N * 4);
  int*      total   = (int*)alloc(256);
  int*      csr_col = (int*)alloc((size_t)E * 4);
  float2*   csr_w   = (float2*)alloc((size_t)E * 8);
  unsigned* xc      = (unsigned*)alloc((size_t)N * 64 * 4);
  unsigned* Hc      = (unsigned*)alloc((size_t)N * 64 * 4);

  hipMemsetAsync(cnt, 0, (size_t)N * 4, stream);
  hipMemsetAsync(total, 0, 4, stream);
  int n4 = N * 64 / 4;
  conv_k<<<(n4 + 255) / 256, 256, 0, stream>>>((const float4*)xr, (const float4*)xi,
                                               (uint4*)xc, n4);
  hist_k<<<(E + 255) / 256, 256, 0, stream>>>(row, cnt, E);
  offs_k<<<(N + 255) / 256, 256, 0, stream>>>(cnt, offs, cursor, total, N);
  scatter_k<<<(E + 255) / 256, 256, 0, stream>>>(row, col, wsym, qp, ent, cc,
                                                 cursor, csr_col, csr_w, E);
  int nb = (N + 63) / 64;  // 4 waves/block x 16 nodes/wave
  layer1_k<<<nb, 256, 0, stream>>>(xc, offs, cnt, csr_col, csr_w, W1, b1, Hc, N);
  layer2_k<<<nb, 256, 0, stream>>>(Hc, offs, cnt, csr_col, csr_w, W2, b2, W3, b3,
                                   out, N);
}

// Round 4
// 267.533 us; speedup vs baseline: 2.3494x; 1.1503x over previous
//
#include <hip/hip_runtime.h>
#include <hip/hip_fp16.h>

// ---------------------------------------------------------------------------
// Complex 2-layer MAP graph conv. Round 3:
//  - streaming gather: wave processes its 16-node group's contiguous edge
//    range in 16-deep double-buffered batches; node boundary (packed in col
//    high bits) flushes the register accumulator to LDS. No per-node tails.
//  - fp16 everywhere (activations, edge weights, MFMA f16) for precision
//    headroom at the same speed.
// ---------------------------------------------------------------------------

typedef __attribute__((ext_vector_type(8))) _Float16 half8;
typedef __attribute__((ext_vector_type(4))) float f32x4;

#define LW 72    // LDS act row stride (halves): 144B rows, 16B-aligned, bank-spread
#define LW3 136  // LDS proj row stride (halves): 272B rows

__device__ __forceinline__ unsigned short hbits(float f) {
  return __half_as_ushort(__float2half_rn(f));
}
__device__ __forceinline__ unsigned packh2(float a, float b) {
  return ((unsigned)hbits(b) << 16) | (unsigned)hbits(a);
}
__device__ __forceinline__ float2 unpackh2(unsigned u) {
  __half2 h = *reinterpret_cast<__half2*>(&u);
  return __half22float2(h);
}

// ---- CSR build ------------------------------------------------------------
__global__ void hist_k(const int* __restrict__ row, int* __restrict__ cnt, int E) {
  int e = blockIdx.x * blockDim.x + threadIdx.x;
  if (e < E) atomicAdd(&cnt[row[e]], 1);
}

__global__ void offs_k(const int* __restrict__ cnt, int* __restrict__ offs,
                       int* __restrict__ cursor, int* __restrict__ total, int N) {
  int n = blockIdx.x * blockDim.x + threadIdx.x;
  int lane = threadIdx.x & 63;
  int v = (n < N) ? cnt[n] : 0;
  int x = v;
#pragma unroll
  for (int d = 1; d < 64; d <<= 1) {
    int t = __shfl_up(x, d);
    if (lane >= d) x += t;
  }
  int excl = x - v;
  int wtot = __shfl(x, 63);
  int base = 0;
  if (lane == 63) base = atomicAdd(total, wtot);
  base = __shfl(base, 63);
  if (n < N) {
    offs[n] = base + excl;
    cursor[n] = base + excl;
  }
}

// col packs group-relative node (row&15) in bits [28:31]
__global__ void scatter_k(const int* __restrict__ row, const int* __restrict__ col,
                          const float* __restrict__ wsym, const float* __restrict__ qp,
                          const float* __restrict__ ent, const float* __restrict__ cc,
                          int* __restrict__ cursor, int* __restrict__ ccol,
                          unsigned* __restrict__ cwh, int E) {
  int e = blockIdx.x * blockDim.x + threadIdx.x;
  if (e >= E) return;
  float ph = qp[0] * (ent[e] + cc[e]);
  float s, c;
  sincosf(ph, &s, &c);
  float w = wsym[e];
  int r = row[e];
  int pos = atomicAdd(&cursor[r], 1);
  ccol[pos] = col[e] | ((r & 15) << 28);
  cwh[pos] = packh2(w * c, w * s);
}

// ---- pack input features to fp16x2 u32 ------------------------------------
__global__ void conv_k(const float4* __restrict__ xr, const float4* __restrict__ xi,
                       uint4* __restrict__ xc, int n4) {
  int i = blockIdx.x * 256 + threadIdx.x;
  if (i >= n4) return;
  float4 r = xr[i], m = xi[i];
  xc[i] = make_uint4(packh2(r.x, m.x), packh2(r.y, m.y), packh2(r.z, m.z), packh2(r.w, m.w));
}

// ---- streaming SPMM(16-node group) + MFMA GEMV ----------------------------
// A-frag (16x16x32 f16): lane holds A[lane&15][(lane>>4)*8+j]; A row = node.
// C/D: col(lane&15)=out-feature, row((lane>>4)*4+reg)=node.
struct AccRI {
  f32x4 r[4], i[4];
};

__device__ __forceinline__ AccRI spmm_gemv(
    const unsigned* __restrict__ tbl,
    const int* __restrict__ offs, const int* __restrict__ cnt,
    const int* __restrict__ ccol, const unsigned* __restrict__ cwh,
    const _Float16* __restrict__ sW,
    _Float16* __restrict__ s_ar, _Float16* __restrict__ s_ai,
    int n0, int N, int lane) {
  const int c16 = lane & 15, q16 = lane >> 4;
  int nlast = n0 + 15;
  if (nlast >= N) nlast = N - 1;
  int ebeg = __builtin_amdgcn_readfirstlane(offs[n0]);
  int eend = __builtin_amdgcn_readfirstlane(offs[nlast] + cnt[nlast]);
  int total = eend - ebeg;

  int colA[16], colB[16];
  unsigned wA[16], wB[16], vA[16], vB[16];
  float ar = 0.f, ai = 0.f;
  int ni = 0;

#define LOADRECS(base_, cols_, ws_)                                   \
  do {                                                                \
    if ((base_) + 16 <= total) {                                      \
      _Pragma("unroll") for (int j = 0; j < 16; ++j) {                \
        (cols_)[j] = ccol[ebeg + (base_) + j];                        \
        (ws_)[j] = cwh[ebeg + (base_) + j];                           \
      }                                                               \
    } else {                                                          \
      _Pragma("unroll") for (int j = 0; j < 16; ++j) {                \
        int idx_ = ((base_) + j < total) ? ebeg + (base_) + j : ebeg; \
        (cols_)[j] = ccol[idx_];                                      \
        (ws_)[j] = cwh[idx_];                                         \
      }                                                               \
    }                                                                 \
  } while (0)

#define ISSUEV(cols_, v_)                                             \
  do {                                                                \
    _Pragma("unroll") for (int j = 0; j < 16; ++j)                    \
        (v_)[j] = tbl[(unsigned)((cols_)[j] & 0x0FFFFFFF) * 64u + lane]; \
  } while (0)

#define FLUSHTO(nrel_)                      \
  while (ni < (nrel_)) {                    \
    s_ar[ni * LW + lane] = (_Float16)ar;    \
    s_ai[ni * LW + lane] = (_Float16)ai;    \
    ar = 0.f;                               \
    ai = 0.f;                               \
    ++ni;                                   \
  }

#define CONSUME(cols_, ws_, v_, base_)                          \
  do {                                                          \
    _Pragma("unroll") for (int j = 0; j < 16; ++j) {            \
      if ((base_) + j >= total) break;                          \
      int u_ = (cols_)[j];                                      \
      int nrel_ = ((unsigned)u_) >> 28;                         \
      FLUSHTO(nrel_);                                           \
      float2 val_ = unpackh2((v_)[j]);                          \
      float2 wv_ = unpackh2((ws_)[j]);                          \
      ar = fmaf(wv_.x, val_.x, fmaf(-wv_.y, val_.y, ar));       \
      ai = fmaf(wv_.y, val_.x, fmaf(wv_.x, val_.y, ai));        \
    }                                                           \
  } while (0)

  int nbatch = (total + 15) >> 4;
  if (nbatch > 0) {
    LOADRECS(0, colA, wA);
    ISSUEV(colA, vA);
    if (nbatch > 1) LOADRECS(16, colB, wB);
    for (int b = 0; b < nbatch; b += 2) {
      if (b + 1 < nbatch) ISSUEV(colB, vB);
      CONSUME(colA, wA, vA, b * 16);
      if (b + 2 < nbatch) LOADRECS((b + 2) * 16, colA, wA);
      if (b + 1 < nbatch) {
        if (b + 2 < nbatch) ISSUEV(colA, vA);
        CONSUME(colB, wB, vB, (b + 1) * 16);
        if (b + 3 < nbatch) LOADRECS((b + 3) * 16, colB, wB);
      }
    }
  }
  FLUSHTO(16);
#undef LOADRECS
#undef ISSUEV
#undef FLUSHTO
#undef CONSUME

  half8 a_r[2], a_i[2];
#pragma unroll
  for (int ks = 0; ks < 2; ++ks) {
    int off = c16 * LW + ks * 32 + q16 * 8;
    a_r[ks] = *(const half8*)&s_ar[off];
    a_i[ks] = *(const half8*)&s_ai[off];
  }
  AccRI acc;
#pragma unroll
  for (int nt = 0; nt < 4; ++nt) {
    acc.r[nt] = (f32x4){0.f, 0.f, 0.f, 0.f};
    acc.i[nt] = (f32x4){0.f, 0.f, 0.f, 0.f};
  }
#pragma unroll
  for (int nt = 0; nt < 4; ++nt)
#pragma unroll
    for (int ks = 0; ks < 2; ++ks) {
      half8 b = *(const half8*)&sW[(nt * 16 + c16) * LW + ks * 32 + q16 * 8];
      acc.r[nt] = __builtin_amdgcn_mfma_f32_16x16x32_f16(a_r[ks], b, acc.r[nt], 0, 0, 0);
      acc.i[nt] = __builtin_amdgcn_mfma_f32_16x16x32_f16(a_i[ks], b, acc.i[nt], 0, 0, 0);
    }
  return acc;
}

// ---- layer 1 --------------------------------------------------------------
__global__ void __launch_bounds__(256, 4) layer1_k(
    const unsigned* __restrict__ xc,
    const int* __restrict__ offs, const int* __restrict__ cnt,
    const int* __restrict__ ccol, const unsigned* __restrict__ cwh,
    const float* __restrict__ W, const float* __restrict__ bias,
    unsigned* __restrict__ Hc, int N) {
  __shared__ __align__(16) _Float16 sW[64 * LW];
  __shared__ __align__(16) _Float16 s_act[4][2][16 * LW];
  for (int i = threadIdx.x; i < 64 * 64; i += 256)
    sW[(i >> 6) * LW + (i & 63)] = (_Float16)W[i];
  __syncthreads();
  const int w = threadIdx.x >> 6, lane = threadIdx.x & 63;
  const int c16 = lane & 15, q16 = lane >> 4;
  int n0 = (blockIdx.x * 4 + w) * 16;
  if (n0 >= N) return;
  float bl[4];
#pragma unroll
  for (int nt = 0; nt < 4; ++nt) bl[nt] = 2.f * bias[nt * 16 + c16];

  AccRI acc = spmm_gemv(xc, offs, cnt, ccol, cwh, sW,
                        &s_act[w][0][0], &s_act[w][1][0], n0, N, lane);
#pragma unroll
  for (int nt = 0; nt < 4; ++nt)
#pragma unroll
    for (int r = 0; r < 4; ++r) {
      int node = n0 + q16 * 4 + r;
      if (node < N) {
        float hr = fmaxf(acc.r[nt][r], 0.f);
        float hi = fmaxf(acc.i[nt][r] + bl[nt], 0.f);
        Hc[(unsigned)node * 64u + nt * 16 + c16] = packh2(hr, hi);
      }
    }
}

// ---- layer 2 + final [16x128] projection ----------------------------------
__global__ void __launch_bounds__(256, 4) layer2_k(
    const unsigned* __restrict__ Hc,
    const int* __restrict__ offs, const int* __restrict__ cnt,
    const int* __restrict__ ccol, const unsigned* __restrict__ cwh,
    const float* __restrict__ W2, const float* __restrict__ b2,
    const float* __restrict__ W3, const float* __restrict__ b3,
    float* __restrict__ out, int N) {
  __shared__ __align__(16) _Float16 sW[64 * LW];
  __shared__ __align__(16) _Float16 sW3p[16 * LW3];
  __shared__ __align__(16) _Float16 s_act[4][2][16 * LW];
  for (int i = threadIdx.x; i < 64 * 64; i += 256)
    sW[(i >> 6) * LW + (i & 63)] = (_Float16)W2[i];
  // interleaved k' = 2f + (0:real,1:imag)  ->  source W3[o][f + 64*ri]
  for (int i = threadIdx.x; i < 16 * 128; i += 256) {
    int o = i >> 7, kp = i & 127;
    sW3p[o * LW3 + kp] = (_Float16)W3[o * 128 + (kp >> 1) + 64 * (kp & 1)];
  }
  __syncthreads();
  const int w = threadIdx.x >> 6, lane = threadIdx.x & 63;
  const int c16 = lane & 15, q16 = lane >> 4;
  int n0 = (blockIdx.x * 4 + w) * 16;
  if (n0 >= N) return;
  float bl[4];
#pragma unroll
  for (int nt = 0; nt < 4; ++nt) bl[nt] = 2.f * b2[nt * 16 + c16];

  AccRI acc = spmm_gemv(Hc, offs, cnt, ccol, cwh, sW,
                        &s_act[w][0][0], &s_act[w][1][0], n0, N, lane);

  // stage h packed (r,i) per feature into proj buffer (reuses act LDS)
  unsigned* pb = (unsigned*)&s_act[w][0][0];  // [16][68] u32 rows = 136 halves
#pragma unroll
  for (int nt = 0; nt < 4; ++nt)
#pragma unroll
    for (int r = 0; r < 4; ++r) {
      float hr = fmaxf(acc.r[nt][r], 0.f);
      float hi = fmaxf(acc.i[nt][r] + bl[nt], 0.f);
      pb[(q16 * 4 + r) * 68 + nt * 16 + c16] = packh2(hr, hi);
    }
  f32x4 po = {0.f, 0.f, 0.f, 0.f};
#pragma unroll
  for (int ks = 0; ks < 4; ++ks) {
    half8 a = *(const half8*)((const _Float16*)pb + c16 * LW3 + ks * 32 + q16 * 8);
    half8 b = *(const half8*)&sW3p[c16 * LW3 + ks * 32 + q16 * 8];
    po = __builtin_amdgcn_mfma_f32_16x16x32_f16(a, b, po, 0, 0, 0);
  }
  float b3v = b3[c16];
#pragma unroll
  for (int r = 0; r < 4; ++r) {
    int node = n0 + q16 * 4 + r;
    if (node < N) out[(unsigned)node * 16u + c16] = po[r] + b3v;
  }
}

extern "C" void kernel_launch(void* const* d_in, const int* in_sizes, int n_in,
                              void* d_out, int out_size, void* d_ws, size_t ws_size,
                              hipStream_t stream) {
  const float* xr   = (const float*)d_in[0];
  const float* xi   = (const float*)d_in[1];
  const float* wsym = (const float*)d_in[2];
  const float* qp   = (const float*)d_in[3];
  const float* ent  = (const float*)d_in[4];
  const float* cc   = (const float*)d_in[5];
  const float* W1   = (const float*)d_in[6];
  const float* b1   = (const float*)d_in[7];
  const float* W2   = (const float*)d_in[8];
  const float* b2   = (const float*)d_in[9];
  const float* W3   = (const float*)d_in[10];
  const float* b3   = (const float*)d_in[11];
  const int*   row  = (const int*)d_in[12];
  const int*   col  = (const int*)d_in[13];
  const int N = in_sizes[0] / 64;
  const int E = in_sizes[2];
  float* out = (float*)d_out;

  char* ws = (char*)d_ws;
  size_t off = 0;
  auto alloc = [&](size_t bytes) -> void* {
    void* p = ws + off;
    off += (bytes + 255) & ~(size_t)255;
    return p;
  };
  int*      cnt    = (int*)alloc((size_t)N * 4);
  int*      offs   = (int*)alloc((size_t)N * 4);
  int*      cursor = (int*)alloc((size_t)N * 4);
  int*      total  = (int*)alloc(256);
  int*      ccol   = (int*)alloc((size_t)E * 4);
  unsigned* cwh    = (unsigned*)alloc((size_t)E * 4);
  unsigned* xc     = (unsigned*)alloc((size_t)N * 64 * 4);
  unsigned* Hc     = (unsigned*)alloc((size_t)N * 64 * 4);

  hipMemsetAsync(cnt, 0, (size_t)N * 4, stream);
  hipMemsetAsync(total, 0, 4, stream);
  int n4 = N * 64 / 4;
  conv_k<<<(n4 + 255) / 256, 256, 0, stream>>>((const float4*)xr, (const float4*)xi,
                                               (uint4*)xc, n4);
  hist_k<<<(E + 255) / 256, 256, 0, stream>>>(row, cnt, E);
  offs_k<<<(N + 255) / 256, 256, 0, stream>>>(cnt, offs, cursor, total, N);
  scatter_k<<<(E + 255) / 256, 256, 0, stream>>>(row, col, wsym, qp, ent, cc,
                                                 cursor, ccol, cwh, E);
  int nb = (N + 63) / 64;  // 4 waves/block x 16 nodes/wave
  layer1_k<<<nb, 256, 0, stream>>>(xc, offs, cnt, ccol, cwh, W1, b1, Hc, N);
  layer2_k<<<nb, 256, 0, stream>>>(Hc, offs, cnt, ccol, cwh, W2, b2, W3, b3,
                                   out, N);
}